// Round 4
// baseline (153.718 us; speedup 1.0000x reference)
//
#include <hip/hip_runtime.h>

constexpr int BB = 8, CC = 512, TT = 8192;
constexpr int TILE = 64;              // t-values per block
constexpr int TPB = TT / TILE;        // 128 tiles per batch
constexpr int NBLK = BB * TPB;        // 1024 blocks
constexpr float MOM = 0.05f, EPSV = 1e-6f;

typedef float v4f __attribute__((ext_vector_type(4)));

// inclusive in-wave scan of affine maps y -> A*y + B (lane order = time order)
__device__ __forceinline__ void wave_incl_affine(float& A, float& B) {
  const int lane = threadIdx.x & 63;
  #pragma unroll
  for (int off = 1; off < 64; off <<= 1) {
    float pA = __shfl_up(A, off, 64);
    float pB = __shfl_up(B, off, 64);
    if (lane >= off) { B = fmaf(A, pB, B); A *= pA; }
  }
}

// Decoupled look-back: compose aggregates of tiles [0, tile) of this batch.
// lane k reads records 2k, 2k+1 (identity-padded), then one wave scan.
// Returns y value entering this tile (y_init = 0).  Waits only on lower
// blockIdx records (monotonic dispatch -> no deadlock).
__device__ __forceinline__ float lookback(const float* __restrict__ wsA,
                                          const float* __restrict__ wsB,
                                          const int* __restrict__ fl,
                                          int rec0, int tile) {
  const int lane = threadIdx.x & 63;
  const int j0 = 2 * lane, j1 = j0 + 1;
  float A = 1.f, B = 0.f;
  if (j0 < tile) {
    while (__hip_atomic_load(&fl[rec0 + j0], __ATOMIC_ACQUIRE,
                             __HIP_MEMORY_SCOPE_AGENT) == 0)
      __builtin_amdgcn_s_sleep(2);
    A = __hip_atomic_load(&wsA[rec0 + j0], __ATOMIC_RELAXED, __HIP_MEMORY_SCOPE_AGENT);
    B = __hip_atomic_load(&wsB[rec0 + j0], __ATOMIC_RELAXED, __HIP_MEMORY_SCOPE_AGENT);
  }
  if (j1 < tile) {
    while (__hip_atomic_load(&fl[rec0 + j1], __ATOMIC_ACQUIRE,
                             __HIP_MEMORY_SCOPE_AGENT) == 0)
      __builtin_amdgcn_s_sleep(2);
    const float A1v = __hip_atomic_load(&wsA[rec0 + j1], __ATOMIC_RELAXED, __HIP_MEMORY_SCOPE_AGENT);
    const float B1v = __hip_atomic_load(&wsB[rec0 + j1], __ATOMIC_RELAXED, __HIP_MEMORY_SCOPE_AGENT);
    B = fmaf(A1v, B, B1v);   // apply j0 first, then j1
    A *= A1v;
  }
  wave_incl_affine(A, B);
  return __shfl(B, 63, 64);  // prefix applied to y_init = 0
}

// One block = (batch b, 64-wide t-tile). x-tile (512c x 64t) lives in regs.
__global__ __launch_bounds__(512) void k_fused(
    const float* __restrict__ x, const float* __restrict__ g,
    const float* __restrict__ Wa, const float* __restrict__ Wb,
    const float* __restrict__ Wo, const float* __restrict__ Bo,
    float* __restrict__ out,
    float* __restrict__ A1, float* __restrict__ B1,
    float* __restrict__ A2, float* __restrict__ B2,
    int* __restrict__ f1, int* __restrict__ f2) {
  __shared__ float lwa[CC], lwb[CC], lwo[CC], lbo[CC];
  __shared__ float red[3][8][TILE];
  __shared__ float xw[32];
  __shared__ float mean_s[TILE], inv_s[TILE];

  const int tid = threadIdx.x;
  const int lane = tid & 63;
  const int wid = tid >> 6;
  const int bidx = blockIdx.x;
  const int b = bidx >> 7;             // / TPB
  const int tile = bidx & (TPB - 1);
  const int rec0 = b << 7;             // first record index of this batch
  const int t0 = tile * TILE;

  // ---- issue x-tile loads first; latency hides under the softmax ----
  // lane = (csub, t-quad): lanes 0-15 t-quads of channel c0, 16-31 c0+1, ...
  const int t4 = (lane & 15) << 2;     // 0..60
  const int csub = lane >> 4;          // 0..3
  const int c0 = (wid << 6) + csub;
  const float* xrow = x + (size_t)b * CC * TT + t0 + t4;
  v4f xv[16];
  #pragma unroll
  for (int i = 0; i < 16; ++i)
    xv[i] = *(const v4f*)(xrow + (size_t)(c0 + (i << 2)) * TT);

  // ---- softmax over C for Wa, Wb (redundant per block); stage Wo/Bo ----
  {
    float va = Wa[tid], vb = Wb[tid];
    lwo[tid] = Wo[tid];
    lbo[tid] = Bo[tid];
    float ma = va, mb = vb;
    #pragma unroll
    for (int off = 32; off > 0; off >>= 1) {
      ma = fmaxf(ma, __shfl_down(ma, off, 64));
      mb = fmaxf(mb, __shfl_down(mb, off, 64));
    }
    if (lane == 0) { xw[wid] = ma; xw[8 + wid] = mb; }
    __syncthreads();
    ma = xw[0]; mb = xw[8];
    #pragma unroll
    for (int w = 1; w < 8; ++w) { ma = fmaxf(ma, xw[w]); mb = fmaxf(mb, xw[8 + w]); }
    const float ea = expf(va - ma), eb = expf(vb - mb);
    float sA = ea, sB = eb;
    #pragma unroll
    for (int off = 32; off > 0; off >>= 1) {
      sA += __shfl_down(sA, off, 64);
      sB += __shfl_down(sB, off, 64);
    }
    if (lane == 0) { xw[16 + wid] = sA; xw[24 + wid] = sB; }
    __syncthreads();
    sA = xw[16]; sB = xw[24];
    #pragma unroll
    for (int w = 1; w < 8; ++w) { sA += xw[16 + w]; sB += xw[24 + w]; }
    lwa[tid] = ea * (1.f / sA);
    lwb[tid] = eb * (1.f / sB);
  }
  __syncthreads();

  // ---- weighted partial sums over this wave's 64 channels ----
  v4f aa = {0.f, 0.f, 0.f, 0.f}, ab = aa, aq = aa;
  #pragma unroll
  for (int i = 0; i < 16; ++i) {
    const int c = c0 + (i << 2);
    const float wac = lwa[c], wbc = lwb[c];
    aa += wac * xv[i];
    ab += wbc * xv[i];
    aq += (wbc * xv[i]) * xv[i];
  }
  // fold the 4 channel subgroups (same t-quad): butterfly xor 16, 32
  #pragma unroll
  for (int k = 0; k < 4; ++k) {
    aa[k] += __shfl_xor(aa[k], 16, 64);
    ab[k] += __shfl_xor(ab[k], 16, 64);
    aq[k] += __shfl_xor(aq[k], 16, 64);
    aa[k] += __shfl_xor(aa[k], 32, 64);
    ab[k] += __shfl_xor(ab[k], 32, 64);
    aq[k] += __shfl_xor(aq[k], 32, 64);
  }
  if (lane < 16) {
    *(v4f*)&red[0][wid][t4] = aa;
    *(v4f*)&red[1][wid][t4] = ab;
    *(v4f*)&red[2][wid][t4] = aq;
  }
  __syncthreads();

  // ---- wave 0: cross-wave reduce, publish aggregates, look-back scans ----
  if (wid == 0) {
    const int t = lane;
    float sa = 0.f, sbv = 0.f, sq = 0.f;
    #pragma unroll
    for (int w = 0; w < 8; ++w) {
      sa  += red[0][w][t];
      sbv += red[1][w][t];
      sq  += red[2][w][t];
    }
    const float gt = g[(size_t)b * TT + t0 + t] * MOM;
    const float a = 1.f - gt;

    // mean EMA: per-step affine (a, gt*sa); publish tile aggregate early
    float Ai = a, Bi = gt * sa;
    wave_incl_affine(Ai, Bi);
    if (lane == 63) {
      A1[bidx] = Ai; B1[bidx] = Bi;
      __hip_atomic_store(&f1[bidx], 1, __ATOMIC_RELEASE, __HIP_MEMORY_SCOPE_AGENT);
    }
    const float mprev = (tile > 0) ? lookback(A1, B1, f1, rec0, tile) : 0.f;
    const float m = fmaf(Ai, mprev, Bi);
    mean_s[t] = m;

    // var EMA input: sb2 - 2*m*sb + m^2  (sum(wb) == 1)
    const float vi = fmaf(m, m, fmaf(-2.f * m, sbv, sq));
    float Ci = a, Di = gt * vi;
    wave_incl_affine(Ci, Di);
    if (lane == 63) {
      A2[bidx] = Ci; B2[bidx] = Di;
      __hip_atomic_store(&f2[bidx], 1, __ATOMIC_RELEASE, __HIP_MEMORY_SCOPE_AGENT);
    }
    const float vprev = (tile > 0) ? lookback(A2, B2, f2, rec0, tile) : 0.f;
    const float vv = fmaf(Ci, vprev, Di);
    inv_s[t] = rsqrtf(vv + EPSV);
  }
  __syncthreads();

  // ---- normalize from registers, write out (single x traffic) ----
  const v4f mval = *(const v4f*)&mean_s[t4];
  const v4f ival = *(const v4f*)&inv_s[t4];
  float* orow = out + (size_t)b * CC * TT + t0 + t4;
  #pragma unroll
  for (int i = 0; i < 16; ++i) {
    const int c = c0 + (i << 2);
    v4f o = (xv[i] - mval) * ival * lwo[c] + lbo[c];
    *(v4f*)(orow + (size_t)c * TT) = o;
  }
}

extern "C" void kernel_launch(void* const* d_in, const int* in_sizes, int n_in,
                              void* d_out, int out_size, void* d_ws, size_t ws_size,
                              hipStream_t stream) {
  const float* x  = (const float*)d_in[0];  // (B, C, T)
  const float* g  = (const float*)d_in[1];  // (B, 1, T)
  const float* Wa = (const float*)d_in[2];  // (1, C, 1)
  const float* Wb = (const float*)d_in[3];  // (1, C, 1)
  const float* Wo = (const float*)d_in[4];  // (C, 1, 1)
  const float* Bo = (const float*)d_in[5];  // (C,)
  float* out = (float*)d_out;

  // ws: flags first (one contiguous memset), then affine aggregates
  int* f1 = (int*)d_ws;
  int* f2 = f1 + NBLK;
  float* A1 = (float*)(f2 + NBLK);
  float* B1 = A1 + NBLK;
  float* A2 = B1 + NBLK;
  float* B2 = A2 + NBLK;

  hipMemsetAsync(d_ws, 0, 2 * NBLK * sizeof(int), stream);  // reset flags each call
  k_fused<<<NBLK, 512, 0, stream>>>(x, g, Wa, Wb, Wo, Bo, out, A1, B1, A2, B2, f1, f2);
}

// Round 5
// 139.342 us; speedup vs baseline: 1.1032x; 1.1032x over previous
//
#include <hip/hip_runtime.h>

constexpr int BB = 8, CC = 512, TT = 8192;
constexpr int TILE = 64;               // t-values per worker block
constexpr int TPB = TT / TILE;         // 128 worker tiles per batch
constexpr int NWORK = BB * TPB;        // 1024 worker blocks
constexpr float MOM = 0.05f, EPSV = 1e-6f;

typedef float v4f __attribute__((ext_vector_type(4)));

__device__ __forceinline__ void wave_incl_affine(float& A, float& B) {
  const int lane = threadIdx.x & 63;
  #pragma unroll
  for (int off = 1; off < 64; off <<= 1) {
    float pA = __shfl_up(A, off, 64);
    float pB = __shfl_up(B, off, 64);
    if (lane >= off) { B = fmaf(A, pB, B); A *= pA; }
  }
}

// block-wide (512 thr) exclusive affine prefix applied to y0 = 0
__device__ __forceinline__ float block_scan_prev(float A, float B,
                                                 float* wAs, float* wBs) {
  const int lane = threadIdx.x & 63, wid = threadIdx.x >> 6;
  wave_incl_affine(A, B);
  __syncthreads();                      // protect scratch from previous call
  if (lane == 63) { wAs[wid] = A; wBs[wid] = B; }
  __syncthreads();
  float cB = 0.f;
  for (int w = 0; w < wid; ++w) cB = fmaf(wAs[w], cB, wBs[w]);
  float leA = __shfl_up(A, 1, 64);
  float leB = __shfl_up(B, 1, 64);
  if (lane == 0) { leA = 1.f; leB = 0.f; }
  return fmaf(leA, cB, leB);
}

__global__ __launch_bounds__(512, 4) void k_fused(
    const float* __restrict__ x, const float* __restrict__ g,
    const float* __restrict__ Wa, const float* __restrict__ Wb,
    const float* __restrict__ Wo, const float* __restrict__ Bo,
    float* __restrict__ out,
    int* __restrict__ cnt1, int* __restrict__ flag2,
    float* __restrict__ sa, float* __restrict__ sb, float* __restrict__ sb2,
    float* __restrict__ mean, float* __restrict__ inv) {
  __shared__ float lwa[CC], lwb[CC], lwo[CC], lbo[CC];
  __shared__ float red[3][8][TILE];
  __shared__ float xw[32];
  __shared__ float wAs[8], wBs[8];
  __shared__ float mean_s[TILE], inv_s[TILE];

  const int tid = threadIdx.x;
  const int lane = tid & 63;
  const int wid = tid >> 6;

  // ================= leader blocks: one per batch, dispatched first ========
  if (blockIdx.x < BB) {
    const int b = blockIdx.x;
    if (tid == 0) {
      while (__hip_atomic_load(&cnt1[b * 16], __ATOMIC_RELAXED,
                               __HIP_MEMORY_SCOPE_AGENT) != TPB)
        __builtin_amdgcn_s_sleep(16);
    }
    __syncthreads();
    __builtin_amdgcn_fence(__ATOMIC_ACQUIRE, "agent");

    constexpr int CH = 16;  // 512 thr * 16 = 8192
    const size_t base = (size_t)b * TT + (size_t)tid * CH;
    float gt[CH], pa[CH];

    float A = 1.f, Bv = 0.f;
    #pragma unroll
    for (int j = 0; j < CH; j += 4) {
      float gv[4]; *(float4*)gv = *(const float4*)(g  + base + j);
      float av[4]; *(float4*)av = *(const float4*)(sa + base + j);
      #pragma unroll
      for (int k = 0; k < 4; ++k) {
        const float gg = gv[k] * MOM;
        gt[j + k] = gg;
        const float p = gg * av[k];
        pa[j + k] = p;
        const float a = 1.f - gg;
        A *= a;
        Bv = fmaf(a, Bv, p);
      }
    }
    float m = block_scan_prev(A, Bv, wAs, wBs);

    float A2 = 1.f, B2 = 0.f;
    #pragma unroll
    for (int j = 0; j < CH; j += 4) {
      float bv[4]; *(float4*)bv = *(const float4*)(sb  + base + j);
      float qv[4]; *(float4*)qv = *(const float4*)(sb2 + base + j);
      float m4[4];
      #pragma unroll
      for (int k = 0; k < 4; ++k) {
        const float a = 1.f - gt[j + k];
        m = fmaf(a, m, pa[j + k]);
        m4[k] = m;
        const float vi = fmaf(m, m, fmaf(-2.f * m, bv[k], qv[k]));  // sum(wb)=1
        const float pv = gt[j + k] * vi;
        pa[j + k] = pv;
        A2 *= a;
        B2 = fmaf(a, B2, pv);
      }
      *(float4*)(mean + base + j) = *(float4*)m4;
    }
    float v = block_scan_prev(A2, B2, wAs, wBs);

    #pragma unroll
    for (int j = 0; j < CH; j += 4) {
      float i4[4];
      #pragma unroll
      for (int k = 0; k < 4; ++k) {
        v = fmaf(1.f - gt[j + k], v, pa[j + k]);
        i4[k] = rsqrtf(v + EPSV);
      }
      *(float4*)(inv + base + j) = *(float4*)i4;
    }
    __syncthreads();  // all mean/inv stores complete (barrier drains vmcnt)
    if (tid == 0)
      __hip_atomic_store(&flag2[b * 16], 1, __ATOMIC_RELEASE,
                         __HIP_MEMORY_SCOPE_AGENT);
    return;
  }

  // ================= worker blocks ==========================================
  const int w = blockIdx.x - BB;
  const int b = w >> 7;                 // / TPB
  const int tile = w & (TPB - 1);
  const int t0 = tile * TILE;

  // issue x-tile loads first; softmax hides under the latency
  const int t4 = (lane & 15) << 2;      // 0..60
  const int csub = lane >> 4;           // 0..3
  const int c0 = (wid << 6) + csub;
  const float* xrow = x + (size_t)b * CC * TT + t0 + t4;
  v4f xv[16];
  #pragma unroll
  for (int i = 0; i < 16; ++i)
    xv[i] = *(const v4f*)(xrow + (size_t)(c0 + (i << 2)) * TT);

  // softmax over C for Wa, Wb (redundant per block); stage Wo/Bo
  {
    float va = Wa[tid], vb = Wb[tid];
    lwo[tid] = Wo[tid];
    lbo[tid] = Bo[tid];
    float ma = va, mb = vb;
    #pragma unroll
    for (int off = 32; off > 0; off >>= 1) {
      ma = fmaxf(ma, __shfl_down(ma, off, 64));
      mb = fmaxf(mb, __shfl_down(mb, off, 64));
    }
    if (lane == 0) { xw[wid] = ma; xw[8 + wid] = mb; }
    __syncthreads();
    ma = xw[0]; mb = xw[8];
    #pragma unroll
    for (int ww = 1; ww < 8; ++ww) { ma = fmaxf(ma, xw[ww]); mb = fmaxf(mb, xw[8 + ww]); }
    const float ea = expf(va - ma), eb = expf(vb - mb);
    float sA = ea, sB = eb;
    #pragma unroll
    for (int off = 32; off > 0; off >>= 1) {
      sA += __shfl_down(sA, off, 64);
      sB += __shfl_down(sB, off, 64);
    }
    if (lane == 0) { xw[16 + wid] = sA; xw[24 + wid] = sB; }
    __syncthreads();
    sA = xw[16]; sB = xw[24];
    #pragma unroll
    for (int ww = 1; ww < 8; ++ww) { sA += xw[16 + ww]; sB += xw[24 + ww]; }
    lwa[tid] = ea * (1.f / sA);
    lwb[tid] = eb * (1.f / sB);
  }
  __syncthreads();

  // weighted partial sums over this wave's 64 channels
  v4f aa = {0.f, 0.f, 0.f, 0.f}, ab = aa, aq = aa;
  #pragma unroll
  for (int i = 0; i < 16; ++i) {
    const int c = c0 + (i << 2);
    const float wac = lwa[c], wbc = lwb[c];
    aa += wac * xv[i];
    ab += wbc * xv[i];
    aq += (wbc * xv[i]) * xv[i];
  }
  #pragma unroll
  for (int k = 0; k < 4; ++k) {
    aa[k] += __shfl_xor(aa[k], 16, 64);
    ab[k] += __shfl_xor(ab[k], 16, 64);
    aq[k] += __shfl_xor(aq[k], 16, 64);
    aa[k] += __shfl_xor(aa[k], 32, 64);
    ab[k] += __shfl_xor(ab[k], 32, 64);
    aq[k] += __shfl_xor(aq[k], 32, 64);
  }
  if (lane < 16) {
    *(v4f*)&red[0][wid][t4] = aa;
    *(v4f*)&red[1][wid][t4] = ab;
    *(v4f*)&red[2][wid][t4] = aq;
  }

  // pin the x-tile in registers across the wait (prevent rematerialization)
  #pragma unroll
  for (int i = 0; i < 16; ++i) asm volatile("" : "+v"(xv[i]));

  __syncthreads();

  // cross-wave fold + publish stats (wave 0), then release-count
  if (wid == 0) {
    float s0 = 0.f, s1 = 0.f, s2 = 0.f;
    #pragma unroll
    for (int ww = 0; ww < 8; ++ww) {
      s0 += red[0][ww][lane];
      s1 += red[1][ww][lane];
      s2 += red[2][ww][lane];
    }
    const size_t dst = (size_t)b * TT + t0 + lane;
    sa[dst] = s0; sb[dst] = s1; sb2[dst] = s2;
  }
  __syncthreads();  // barrier drains vmcnt: stats globally issued
  if (tid == 0)
    __hip_atomic_fetch_add(&cnt1[b * 16], 1, __ATOMIC_RELEASE,
                           __HIP_MEMORY_SCOPE_AGENT);

  // wait for this batch's mean/inv (single flag, relaxed polling)
  if (tid == 0) {
    while (__hip_atomic_load(&flag2[b * 16], __ATOMIC_RELAXED,
                             __HIP_MEMORY_SCOPE_AGENT) == 0)
      __builtin_amdgcn_s_sleep(16);
  }
  __syncthreads();
  __builtin_amdgcn_fence(__ATOMIC_ACQUIRE, "agent");

  // stage mean/inv tile to LDS
  if (tid < 16)
    *(float4*)&mean_s[tid * 4] = *(const float4*)(mean + (size_t)b * TT + t0 + tid * 4);
  else if (tid < 32)
    *(float4*)&inv_s[(tid - 16) * 4] = *(const float4*)(inv + (size_t)b * TT + t0 + (tid - 16) * 4);
  __syncthreads();

  // normalize from registers, single out write
  const v4f mval = *(const v4f*)&mean_s[t4];
  const v4f ival = *(const v4f*)&inv_s[t4];
  float* orow = out + (size_t)b * CC * TT + t0 + t4;
  #pragma unroll
  for (int i = 0; i < 16; ++i) {
    const int c = c0 + (i << 2);
    v4f o = (xv[i] - mval) * ival * lwo[c] + lbo[c];
    __builtin_nontemporal_store(o, (v4f*)(orow + (size_t)c * TT));
  }
}

extern "C" void kernel_launch(void* const* d_in, const int* in_sizes, int n_in,
                              void* d_out, int out_size, void* d_ws, size_t ws_size,
                              hipStream_t stream) {
  const float* x  = (const float*)d_in[0];  // (B, C, T)
  const float* g  = (const float*)d_in[1];  // (B, 1, T)
  const float* Wa = (const float*)d_in[2];  // (1, C, 1)
  const float* Wb = (const float*)d_in[3];  // (1, C, 1)
  const float* Wo = (const float*)d_in[4];  // (C, 1, 1)
  const float* Bo = (const float*)d_in[5];  // (C,)
  float* out = (float*)d_out;

  constexpr int BT = BB * TT;
  int* cnt1  = (int*)d_ws;                  // BB entries, 64-B spaced
  int* flag2 = cnt1 + BB * 16;
  float* sa   = (float*)(flag2 + BB * 16);  // BT
  float* sb   = sa + BT;
  float* sb2  = sb + BT;
  float* mean = sb2 + BT;
  float* inv  = mean + BT;

  hipMemsetAsync(d_ws, 0, 2 * BB * 16 * sizeof(int), stream);  // reset sync state
  k_fused<<<BB + NWORK, 512, 0, stream>>>(x, g, Wa, Wb, Wo, Bo, out,
                                          cnt1, flag2, sa, sb, sb2, mean, inv);
}

// Round 6
// 92.124 us; speedup vs baseline: 1.6686x; 1.5126x over previous
//
#include <hip/hip_runtime.h>

constexpr int BB = 8, CC = 512, TT = 8192;
constexpr int LOG_T = 13, LOG_C = 9;
constexpr int TPB = 32;                // t-tiles per batch (256 t each)
constexpr int TILE_T = TT / TPB;       // 256
constexpr float MOM = 0.05f, EPSV = 1e-6f;

typedef float v4f __attribute__((ext_vector_type(4)));

__device__ __forceinline__ void wave_incl_affine(float& A, float& B) {
  const int lane = threadIdx.x & 63;
  #pragma unroll
  for (int off = 1; off < 64; off <<= 1) {
    float pA = __shfl_up(A, off, 64);
    float pB = __shfl_up(B, off, 64);
    if (lane >= off) { B = fmaf(A, pB, B); A *= pA; }
  }
}

// block-wide (512 thr) exclusive affine prefix applied to y0 = 0
__device__ __forceinline__ float block_scan_prev(float A, float B,
                                                 float* wAs, float* wBs) {
  const int lane = threadIdx.x & 63, wid = threadIdx.x >> 6;
  wave_incl_affine(A, B);
  __syncthreads();
  if (lane == 63) { wAs[wid] = A; wBs[wid] = B; }
  __syncthreads();
  float cB = 0.f;
  for (int w = 0; w < wid; ++w) cB = fmaf(wAs[w], cB, wBs[w]);
  float leA = __shfl_up(A, 1, 64);
  float leB = __shfl_up(B, 1, 64);
  if (lane == 0) { leA = 1.f; leB = 0.f; }
  return fmaf(leA, cB, leB);
}

// K1: weighted C-reductions per (b,t); the LAST block of each batch to finish
// also runs the two gated-EMA scans for that batch (no block ever waits).
__global__ __launch_bounds__(512) void k_reduce(
    const float* __restrict__ x, const float* __restrict__ g,
    const float* __restrict__ Wa, const float* __restrict__ Wb,
    float* __restrict__ sa, float* __restrict__ sb, float* __restrict__ sb2,
    float* __restrict__ mean, float* __restrict__ inv,
    int* __restrict__ cnt) {
  __shared__ float lwa[CC], lwb[CC];
  __shared__ float red[3][8][TILE_T];
  __shared__ float xw[32];
  __shared__ float wAs[8], wBs[8];
  __shared__ int is_last_s;

  const int tid = threadIdx.x;
  const int lane = tid & 63;
  const int wid = tid >> 6;
  const int b = blockIdx.x >> 5;           // / TPB
  const int tile = blockIdx.x & (TPB - 1);
  const int t0 = tile * TILE_T;

  // --- softmax over C for Wa, Wb (redundant per block, hidden by loads) ---
  {
    float va = Wa[tid], vb = Wb[tid];
    float ma = va, mb = vb;
    #pragma unroll
    for (int off = 32; off > 0; off >>= 1) {
      ma = fmaxf(ma, __shfl_down(ma, off, 64));
      mb = fmaxf(mb, __shfl_down(mb, off, 64));
    }
    if (lane == 0) { xw[wid] = ma; xw[8 + wid] = mb; }
    __syncthreads();
    ma = xw[0]; mb = xw[8];
    #pragma unroll
    for (int w = 1; w < 8; ++w) { ma = fmaxf(ma, xw[w]); mb = fmaxf(mb, xw[8 + w]); }
    const float ea = expf(va - ma), eb = expf(vb - mb);
    float sA = ea, sB = eb;
    #pragma unroll
    for (int off = 32; off > 0; off >>= 1) {
      sA += __shfl_down(sA, off, 64);
      sB += __shfl_down(sB, off, 64);
    }
    if (lane == 0) { xw[16 + wid] = sA; xw[24 + wid] = sB; }
    __syncthreads();
    sA = xw[16]; sB = xw[24];
    #pragma unroll
    for (int w = 1; w < 8; ++w) { sA += xw[16 + w]; sB += xw[24 + w]; }
    lwa[tid] = ea * (1.f / sA);
    lwb[tid] = eb * (1.f / sB);
  }
  __syncthreads();

  // --- weighted reduction: wave wid covers channels [wid*64, +64),
  //     lane covers t = t0 + lane*4 .. +3 ---
  const int t4 = lane * 4;
  const int cbase = wid * 64;
  const float* xp = x + ((size_t)(b * CC + cbase)) * TT + t0 + t4;
  float a0=0,a1=0,a2=0,a3=0, b0=0,b1=0,b2=0,b3=0, q0=0,q1=0,q2=0,q3=0;
  #pragma unroll 8
  for (int cc = 0; cc < 64; ++cc) {
    float4 xv = *(const float4*)(xp + (size_t)cc * TT);
    const float wac = lwa[cbase + cc], wbc = lwb[cbase + cc];
    a0 = fmaf(wac, xv.x, a0); a1 = fmaf(wac, xv.y, a1);
    a2 = fmaf(wac, xv.z, a2); a3 = fmaf(wac, xv.w, a3);
    b0 = fmaf(wbc, xv.x, b0); b1 = fmaf(wbc, xv.y, b1);
    b2 = fmaf(wbc, xv.z, b2); b3 = fmaf(wbc, xv.w, b3);
    q0 = fmaf(wbc * xv.x, xv.x, q0); q1 = fmaf(wbc * xv.y, xv.y, q1);
    q2 = fmaf(wbc * xv.z, xv.z, q2); q3 = fmaf(wbc * xv.w, xv.w, q3);
  }
  red[0][wid][t4+0]=a0; red[0][wid][t4+1]=a1; red[0][wid][t4+2]=a2; red[0][wid][t4+3]=a3;
  red[1][wid][t4+0]=b0; red[1][wid][t4+1]=b1; red[1][wid][t4+2]=b2; red[1][wid][t4+3]=b3;
  red[2][wid][t4+0]=q0; red[2][wid][t4+1]=q1; red[2][wid][t4+2]=q2; red[2][wid][t4+3]=q3;
  __syncthreads();

  if (tid < 64) {
    const int o = tid * 4;
    float oa[4] = {0,0,0,0}, ob[4] = {0,0,0,0}, oq[4] = {0,0,0,0};
    #pragma unroll
    for (int w = 0; w < 8; ++w) {
      #pragma unroll
      for (int k = 0; k < 4; ++k) {
        oa[k] += red[0][w][o+k];
        ob[k] += red[1][w][o+k];
        oq[k] += red[2][w][o+k];
      }
    }
    const size_t dst = (size_t)b * TT + t0 + o;
    *(float4*)(sa  + dst) = make_float4(oa[0], oa[1], oa[2], oa[3]);
    *(float4*)(sb  + dst) = make_float4(ob[0], ob[1], ob[2], ob[3]);
    *(float4*)(sb2 + dst) = make_float4(oq[0], oq[1], oq[2], oq[3]);
  }
  __syncthreads();  // all stat stores issued by all waves

  // --- last-arriver election (release makes our stats visible first) ---
  if (tid == 0) {
    const int old = __hip_atomic_fetch_add(&cnt[b * 16], 1, __ATOMIC_RELEASE,
                                           __HIP_MEMORY_SCOPE_AGENT);
    is_last_s = (old == TPB - 1);
  }
  __syncthreads();
  if (!is_last_s) return;

  // --- this block is last for batch b: run both EMA scans over full T ---
  __builtin_amdgcn_fence(__ATOMIC_ACQUIRE, "agent");
  constexpr int CH = 16;  // 512 thr * 16 = 8192
  const size_t base = (size_t)b * TT + (size_t)tid * CH;
  float gt[CH], pa[CH];

  float A = 1.f, Bv = 0.f;
  #pragma unroll
  for (int j = 0; j < CH; j += 4) {
    float gv[4]; *(float4*)gv = *(const float4*)(g  + base + j);
    float av[4]; *(float4*)av = *(const float4*)(sa + base + j);
    #pragma unroll
    for (int k = 0; k < 4; ++k) {
      const float gg = gv[k] * MOM;
      gt[j + k] = gg;
      const float p = gg * av[k];
      pa[j + k] = p;
      const float a = 1.f - gg;
      A *= a;
      Bv = fmaf(a, Bv, p);
    }
  }
  float m = block_scan_prev(A, Bv, wAs, wBs);

  float A2 = 1.f, B2 = 0.f;
  #pragma unroll
  for (int j = 0; j < CH; j += 4) {
    float bv[4]; *(float4*)bv = *(const float4*)(sb  + base + j);
    float qv[4]; *(float4*)qv = *(const float4*)(sb2 + base + j);
    float m4[4];
    #pragma unroll
    for (int k = 0; k < 4; ++k) {
      const float a = 1.f - gt[j + k];
      m = fmaf(a, m, pa[j + k]);
      m4[k] = m;
      const float vi = fmaf(m, m, fmaf(-2.f * m, bv[k], qv[k]));  // sum(wb)=1
      const float pv = gt[j + k] * vi;
      pa[j + k] = pv;
      A2 *= a;
      B2 = fmaf(a, B2, pv);
    }
    *(float4*)(mean + base + j) = *(float4*)m4;
  }
  float v = block_scan_prev(A2, B2, wAs, wBs);

  #pragma unroll
  for (int j = 0; j < CH; j += 4) {
    float i4[4];
    #pragma unroll
    for (int k = 0; k < 4; ++k) {
      v = fmaf(1.f - gt[j + k], v, pa[j + k]);
      i4[k] = rsqrtf(v + EPSV);
    }
    *(float4*)(inv + base + j) = *(float4*)i4;
  }
}

// K2: pointwise normalize. REVERSE traversal: read the MRU tail of x first so
// out-write allocations evict behind the read pointer, not ahead of it.
__global__ __launch_bounds__(256) void k_out(const float* __restrict__ x,
                                             const float* __restrict__ mean,
                                             const float* __restrict__ inv,
                                             const float* __restrict__ wo,
                                             const float* __restrict__ bo,
                                             float* __restrict__ out) {
  const int rev = gridDim.x - 1 - blockIdx.x;
  const size_t base4 = (size_t)rev * 1024 + threadIdx.x;
  #pragma unroll
  for (int j = 0; j < 4; ++j) {
    const size_t idx = base4 + (size_t)j * 256;
    const size_t flat = idx * 4;
    const int t = (int)(flat & (TT - 1));
    const size_t rem = flat >> LOG_T;
    const int c = (int)(rem & (CC - 1));
    const int b = (int)(rem >> LOG_C);
    float4 xv = *(const float4*)(x + flat);
    const size_t mi = ((size_t)b << LOG_T) + t;
    float4 m4 = *(const float4*)(mean + mi);
    float4 i4 = *(const float4*)(inv + mi);
    const float w = wo[c], bb = bo[c];
    v4f o;
    o.x = fmaf((xv.x - m4.x) * i4.x, w, bb);
    o.y = fmaf((xv.y - m4.y) * i4.y, w, bb);
    o.z = fmaf((xv.z - m4.z) * i4.z, w, bb);
    o.w = fmaf((xv.w - m4.w) * i4.w, w, bb);
    __builtin_nontemporal_store(o, (v4f*)(out + flat));
  }
}

extern "C" void kernel_launch(void* const* d_in, const int* in_sizes, int n_in,
                              void* d_out, int out_size, void* d_ws, size_t ws_size,
                              hipStream_t stream) {
  const float* x  = (const float*)d_in[0];  // (B, C, T)
  const float* g  = (const float*)d_in[1];  // (B, 1, T)
  const float* Wa = (const float*)d_in[2];  // (1, C, 1)
  const float* Wb = (const float*)d_in[3];  // (1, C, 1)
  const float* Wo = (const float*)d_in[4];  // (C, 1, 1)
  const float* Bo = (const float*)d_in[5];  // (C,)
  float* out = (float*)d_out;

  constexpr int BT = BB * TT;
  int* cnt    = (int*)d_ws;                 // BB counters, 64-B spaced
  float* sa   = (float*)(cnt + BB * 16);    // BT
  float* sb   = sa + BT;
  float* sb2  = sb + BT;
  float* mean = sb2 + BT;
  float* inv  = mean + BT;

  hipMemsetAsync(d_ws, 0, BB * 16 * sizeof(int), stream);  // reset counters
  k_reduce<<<BB * TPB, 512, 0, stream>>>(x, g, Wa, Wb, sa, sb, sb2, mean, inv, cnt);
  k_out<<<8192, 256, 0, stream>>>(x, mean, inv, Wo, Bo, out);
}